// Round 8
// baseline (504.887 us; speedup 1.0000x reference)
//
#include <hip/hip_runtime.h>
#include <math.h>

#define HID 128
#define NOUT 10
#define NG 1000
#define SCAN_B 256

typedef unsigned short u16;
typedef __attribute__((ext_vector_type(8))) short bf16x8;
typedef __attribute__((ext_vector_type(4))) float f32x4;

__device__ inline u16 f2bf(float f) {
    unsigned x = __float_as_uint(f);
    return (u16)((x + 0x7FFF + ((x >> 16) & 1)) >> 16);  // RNE
}
__device__ inline float bf2f(u16 b) { return __uint_as_float(((unsigned)b) << 16); }

__global__ void k_zero(float* __restrict__ p, int n) {
    int i = blockIdx.x * 256 + threadIdx.x;
    if (i < n) p[i] = 0.f;
}

// counts[d]++ AND capture per-edge rank (position within its dst bucket)
__global__ void k_count_rank(const int* __restrict__ ei, int* __restrict__ counts,
                             int* __restrict__ rank, int E) {
    int e = blockIdx.x * 256 + threadIdx.x;
    if (e < E) rank[e] = atomicAdd(&counts[ei[(size_t)E + e]], 1);
}

__global__ void k_dinv(const int* __restrict__ counts, float* __restrict__ dinv, int N) {
    int v = blockIdx.x * 256 + threadIdx.x;
    if (v < N) dinv[v] = rsqrtf((float)(counts[v] + 1));  // +1 self-loop
}

__global__ __launch_bounds__(SCAN_B) void k_scan1(const int* __restrict__ counts,
                                                  int* __restrict__ rowptr,
                                                  int* __restrict__ bsum, int N) {
    __shared__ int s[SCAN_B];
    int t = threadIdx.x;
    int i = blockIdx.x * SCAN_B + t;
    int v = (i < N) ? counts[i] : 0;
    s[t] = v;
    __syncthreads();
    for (int off = 1; off < SCAN_B; off <<= 1) {
        int u = (t >= off) ? s[t - off] : 0;
        __syncthreads();
        s[t] += u;
        __syncthreads();
    }
    if (i < N) rowptr[i] = s[t] - v;
    if (t == SCAN_B - 1) bsum[blockIdx.x] = s[t];
}

__global__ __launch_bounds__(512) void k_scan2(int* __restrict__ bsum, int nb) {
    __shared__ int s[512];
    int t = threadIdx.x;
    int v = (t < nb) ? bsum[t] : 0;
    s[t] = v;
    __syncthreads();
    for (int off = 1; off < 512; off <<= 1) {
        int u = (t >= off) ? s[t - off] : 0;
        __syncthreads();
        s[t] += u;
        __syncthreads();
    }
    if (t < nb) bsum[t] = s[t] - v;
}

__global__ void k_scan3(int* __restrict__ rowptr, const int* __restrict__ bsum, int N, int E) {
    int i = blockIdx.x * SCAN_B + threadIdx.x;
    if (i < N) rowptr[i] += bsum[blockIdx.x];
    if (i == 0) rowptr[N] = E;
}

// sorted[rowptr[d] + rank[e]] = src   (no atomics)
__global__ void k_scatter(const int* __restrict__ ei, const int* __restrict__ rank,
                          const int* __restrict__ rowptr, int* __restrict__ sorted, int E) {
    int e = blockIdx.x * 256 + threadIdx.x;
    if (e >= E) return;
    int s = ei[e];
    int d = ei[(size_t)E + e];
    sorted[rowptr[d] + rank[e]] = s;
}

__global__ void k_bounds(const int* __restrict__ batch, int* __restrict__ gstart, int N) {
    int i = blockIdx.x * 256 + threadIdx.x;
    if (i >= N) return;
    int cur = batch[i];
    if (i == 0) {
        for (int g = 0; g <= cur; ++g) gstart[g] = 0;
    } else {
        int prev = batch[i - 1];
        for (int g = prev + 1; g <= cur; ++g) gstart[g] = i;
    }
    if (i == N - 1) {
        for (int g = cur + 1; g <= NG; ++g) gstart[g] = N;
    }
}

// Pre-pack W[K][128] into lane-major MFMA B-fragments, hi/lo bf16 split.
template<int K>
__global__ void k_wsplit(const float* __restrict__ W, u16* __restrict__ whi, u16* __restrict__ wlo) {
    int idx = blockIdx.x * 256 + threadIdx.x;
    if (idx >= K * HID) return;
    int k = idx >> 7;
    int col = idx & 127;
    float v = W[idx];
    u16 hb = f2bf(v);
    u16 lb = f2bf(v - bf2f(hb));
    int ks = k >> 5;
    int kq = (k >> 3) & 3;
    int j = k & 7;
    int c = col >> 4;
    int r = col & 15;
    int lane = kq * 16 + r;
    size_t pos = ((size_t)(ks * 8 + c) * 64 + lane) * 8 + j;
    whi[pos] = hb;
    wlo[pos] = lb;
}

// g(bf16)[N][128] = dinv[row] * ((relu?)(in[N][K]) @ W) via MFMA hi/lo split.
// 32 rows per wave (2 row-groups share every B-fragment load -> half L2 traffic).
template<int K, bool RELU_IN>
__global__ __launch_bounds__(256, 2) void k_gemm_mfma(const float* __restrict__ in,
                                                      const u16* __restrict__ whi,
                                                      const u16* __restrict__ wlo,
                                                      const float* __restrict__ dinv,
                                                      u16* __restrict__ g, int N) {
    constexpr int NKS = K / 32;
    const int w = threadIdx.x >> 6;
    const int l = threadIdx.x & 63;
    const int row0 = blockIdx.x * 128 + w * 32;
    const int r = l & 15;
    const int q = l >> 4;

    bf16x8 ahi[2][NKS], alo[2][NKS];
#pragma unroll
    for (int rg = 0; rg < 2; ++rg) {
        int arow = row0 + rg * 16 + r;
        if (arow > N - 1) arow = N - 1;
        const float* ap = in + (size_t)arow * K + q * 8;
#pragma unroll
        for (int ks = 0; ks < NKS; ++ks) {
            float4 v0 = *(const float4*)(ap + ks * 32);
            float4 v1 = *(const float4*)(ap + ks * 32 + 4);
            float va[8] = {v0.x, v0.y, v0.z, v0.w, v1.x, v1.y, v1.z, v1.w};
#pragma unroll
            for (int j = 0; j < 8; ++j) {
                float f = va[j];
                if (RELU_IN) f = fmaxf(f, 0.f);
                u16 hb = f2bf(f);
                ahi[rg][ks][j] = (short)hb;
                alo[rg][ks][j] = (short)f2bf(f - bf2f(hb));
            }
        }
    }

    f32x4 acc[2][8];
#pragma unroll
    for (int rg = 0; rg < 2; ++rg)
#pragma unroll
        for (int c = 0; c < 8; ++c) acc[rg][c] = (f32x4){0.f, 0.f, 0.f, 0.f};

    const bf16x8* whiv = (const bf16x8*)whi;
    const bf16x8* wlov = (const bf16x8*)wlo;

#pragma unroll
    for (int ks = 0; ks < NKS; ++ks) {
#pragma unroll
        for (int c = 0; c < 8; ++c) {
            bf16x8 b = whiv[(size_t)(ks * 8 + c) * 64 + l];
#pragma unroll
            for (int rg = 0; rg < 2; ++rg) {
                acc[rg][c] = __builtin_amdgcn_mfma_f32_16x16x32_bf16(ahi[rg][ks], b, acc[rg][c], 0, 0, 0);
                acc[rg][c] = __builtin_amdgcn_mfma_f32_16x16x32_bf16(alo[rg][ks], b, acc[rg][c], 0, 0, 0);
            }
        }
    }
#pragma unroll
    for (int ks = 0; ks < NKS; ++ks) {
#pragma unroll
        for (int c = 0; c < 8; ++c) {
            bf16x8 b = wlov[(size_t)(ks * 8 + c) * 64 + l];
#pragma unroll
            for (int rg = 0; rg < 2; ++rg)
                acc[rg][c] = __builtin_amdgcn_mfma_f32_16x16x32_bf16(ahi[rg][ks], b, acc[rg][c], 0, 0, 0);
        }
    }

    // epilogue: scale row by dinv, store bf16. D row=rg*16+(l>>4)*4+i, col=c*16+(l&15)
#pragma unroll
    for (int rg = 0; rg < 2; ++rg) {
        float dv[4];
#pragma unroll
        for (int i = 0; i < 4; ++i) {
            int rr = row0 + rg * 16 + q * 4 + i;
            dv[i] = (rr < N) ? dinv[rr] : 0.f;
        }
#pragma unroll
        for (int c = 0; c < 8; ++c) {
#pragma unroll
            for (int i = 0; i < 4; ++i) {
                int rr = row0 + rg * 16 + q * 4 + i;
                if (rr < N) g[(size_t)rr * HID + c * 16 + r] = f2bf(acc[rg][c][i] * dv[i]);
            }
        }
    }
}

// out[v] = b + dinv[v] * (g[v] + sum_{s in in-edges(v)} g[s])
// One wave64 per node; 4 quarter-wave streams; 4-deep unroll = 16 gathers in flight.
#define BFACC(a, p)                                   \
    a[0] += __uint_as_float((p).x << 16);             \
    a[1] += __uint_as_float((p).x & 0xffff0000u);     \
    a[2] += __uint_as_float((p).y << 16);             \
    a[3] += __uint_as_float((p).y & 0xffff0000u);     \
    a[4] += __uint_as_float((p).z << 16);             \
    a[5] += __uint_as_float((p).z & 0xffff0000u);     \
    a[6] += __uint_as_float((p).w << 16);             \
    a[7] += __uint_as_float((p).w & 0xffff0000u);

__global__ __launch_bounds__(256) void k_aggr(const int* __restrict__ rowptr,
                                              const int* __restrict__ sorted,
                                              const u16* __restrict__ g,
                                              const float* __restrict__ dinv,
                                              const float* __restrict__ b,
                                              float* __restrict__ out, int N) {
    int wid = threadIdx.x >> 6;
    int lane = threadIdx.x & 63;
    int v = blockIdx.x * 4 + wid;
    if (v >= N) return;
    int qq = lane >> 4;              // edge stream 0..3
    int r = lane & 15;
    int c8 = r * 8;

    float a0[8], a1[8], a2[8], a3[8];
#pragma unroll
    for (int i = 0; i < 8; ++i) { a0[i] = 0.f; a1[i] = 0.f; a2[i] = 0.f; a3[i] = 0.f; }

    int beg = rowptr[v], end = rowptr[v + 1];
    int j = beg + qq;
    for (; j + 12 < end; j += 16) {
        int s0 = sorted[j];
        int s1 = sorted[j + 4];
        int s2 = sorted[j + 8];
        int s3 = sorted[j + 12];
        uint4 p0 = *(const uint4*)&g[(size_t)s0 * HID + c8];
        uint4 p1 = *(const uint4*)&g[(size_t)s1 * HID + c8];
        uint4 p2 = *(const uint4*)&g[(size_t)s2 * HID + c8];
        uint4 p3 = *(const uint4*)&g[(size_t)s3 * HID + c8];
        BFACC(a0, p0); BFACC(a1, p1); BFACC(a2, p2); BFACC(a3, p3);
    }
    for (; j < end; j += 4) {
        int s0 = sorted[j];
        uint4 p0 = *(const uint4*)&g[(size_t)s0 * HID + c8];
        BFACC(a0, p0);
    }

#pragma unroll
    for (int i = 0; i < 8; ++i) {
        float t = (a0[i] + a1[i]) + (a2[i] + a3[i]);
        t += __shfl_xor(t, 16);
        t += __shfl_xor(t, 32);
        a0[i] = t;
    }

    if (qq == 0) {
        uint4 sv = *(const uint4*)&g[(size_t)v * HID + c8];
        float se[8];
        se[0] = __uint_as_float(sv.x << 16); se[1] = __uint_as_float(sv.x & 0xffff0000u);
        se[2] = __uint_as_float(sv.y << 16); se[3] = __uint_as_float(sv.y & 0xffff0000u);
        se[4] = __uint_as_float(sv.z << 16); se[5] = __uint_as_float(sv.z & 0xffff0000u);
        se[6] = __uint_as_float(sv.w << 16); se[7] = __uint_as_float(sv.w & 0xffff0000u);
        float dv = dinv[v];
        float4 bv0 = *(const float4*)&b[c8];
        float4 bv1 = *(const float4*)&b[c8 + 4];
        float4 o0, o1;
        o0.x = bv0.x + dv * (a0[0] + se[0]);
        o0.y = bv0.y + dv * (a0[1] + se[1]);
        o0.z = bv0.z + dv * (a0[2] + se[2]);
        o0.w = bv0.w + dv * (a0[3] + se[3]);
        o1.x = bv1.x + dv * (a0[4] + se[4]);
        o1.y = bv1.y + dv * (a0[5] + se[5]);
        o1.z = bv1.z + dv * (a0[6] + se[6]);
        o1.w = bv1.w + dv * (a0[7] + se[7]);
        *(float4*)&out[(size_t)v * HID + c8] = o0;
        *(float4*)&out[(size_t)v * HID + c8 + 4] = o1;
    }
}

// fused mean-pool (relu on load) + classifier
__global__ __launch_bounds__(256) void k_poolfinal(const float* __restrict__ h,
                                                   const int* __restrict__ gstart,
                                                   const float* __restrict__ Wl,
                                                   const float* __restrict__ bl,
                                                   float* __restrict__ out) {
    __shared__ float pool[HID];
    int g = blockIdx.x;
    int t = threadIdx.x;
    int col = t & 127;
    int grp = t >> 7;
    int beg = gstart[g], end = gstart[g + 1];

    float acc = 0.f;
    for (int i = beg + grp; i < end; i += 2)
        acc += fmaxf(h[(size_t)i * HID + col], 0.f);

    if (grp == 1) pool[col] = acc;
    __syncthreads();
    if (grp == 0) {
        float tot = acc + pool[col];
        float c = fmaxf((float)(end - beg), 1.0f);
        pool[col] = tot / c;
    }
    __syncthreads();
    if (t < NOUT) {
        float a = bl[t];
        for (int k = 0; k < HID; ++k) a += pool[k] * Wl[k * NOUT + t];
        out[g * NOUT + t] = a;
    }
}

__global__ void k_probe(float* __restrict__ out, int n, float val) {
    int i = blockIdx.x * 256 + threadIdx.x;
    if (i < n) out[i] = val;
}

extern "C" void kernel_launch(void* const* d_in, const int* in_sizes, int n_in,
                              void* d_out, int out_size, void* d_ws, size_t ws_size,
                              hipStream_t stream) {
    const float* x    = (const float*)d_in[0];
    const int* ei     = (const int*)d_in[1];     // int64 ref -> int32 device
    const int* batch  = (const int*)d_in[2];
    const float* W1 = (const float*)d_in[3];
    const float* b1 = (const float*)d_in[4];
    const float* W2 = (const float*)d_in[5];
    const float* b2 = (const float*)d_in[6];
    const float* W3 = (const float*)d_in[7];
    const float* b3 = (const float*)d_in[8];
    const float* Wl = (const float*)d_in[9];
    const float* bl = (const float*)d_in[10];
    float* out = (float*)d_out;

    const int N = in_sizes[0] / 64;   // 100000
    const int E = in_sizes[1] / 2;    // 1600000

    // workspace layout (bytes)
    char* ws = (char*)d_ws;
    const size_t off_dinv   = 0;                        // N*4
    const size_t off_counts = 400000;                   // N*4
    const size_t off_rowptr = 800000;                   // (N+1)*4
    const size_t off_rank   = 1200128;                  // E*4
    const size_t off_bsum   = 7600128;                  // 512*4
    const size_t off_gstart = 7602176;                  // (NG+1)*4
    const size_t off_sorted = 7606400;                  // E*4
    const size_t off_hW     = 14006400;                 // N*HID*2
    const size_t off_bufB   = 39606400;                 // N*HID*4
    const size_t off_wf1h   = 90806400;                 // 64*128*2
    const size_t off_wf1l   = 90822784;
    const size_t off_wf2h   = 90839168;                 // 128*128*2
    const size_t off_wf2l   = 90871936;
    const size_t off_wf3h   = 90904704;
    const size_t off_wf3l   = 90937472;
    const size_t need       = 90970240;                 // ~91.0 MB

    if (ws_size < need) {
        float enc = (float)(ws_size >> 20);
        k_probe<<<(out_size + 255) / 256, 256, 0, stream>>>(out, out_size, enc);
        return;
    }

    float* dinv  = (float*)(ws + off_dinv);
    int* counts  = (int*)(ws + off_counts);
    int* rowptr  = (int*)(ws + off_rowptr);
    int* rank    = (int*)(ws + off_rank);
    int* bsum    = (int*)(ws + off_bsum);
    int* gstart  = (int*)(ws + off_gstart);
    int* sorted  = (int*)(ws + off_sorted);
    u16* hW      = (u16*)(ws + off_hW);
    float* bufB  = (float*)(ws + off_bufB);
    u16* wf1h = (u16*)(ws + off_wf1h);  u16* wf1l = (u16*)(ws + off_wf1l);
    u16* wf2h = (u16*)(ws + off_wf2h);  u16* wf2l = (u16*)(ws + off_wf2l);
    u16* wf3h = (u16*)(ws + off_wf3h);  u16* wf3l = (u16*)(ws + off_wf3l);

    dim3 blk(256);
    const int gN = (N + 255) / 256;
    const int gE = (E + 255) / 256;
    const int nScanBlk = (N + SCAN_B - 1) / SCAN_B;
    const int mfmaGrid = (N + 127) / 128;             // 128 rows per block (32/wave)
    const int aggrGrid = (N + 3) / 4;

    // ---- CSR build + weight fragment packing ----
    k_zero<<<gN, blk, 0, stream>>>((float*)counts, N);
    k_count_rank<<<gE, blk, 0, stream>>>(ei, counts, rank, E);
    k_dinv<<<gN, blk, 0, stream>>>(counts, dinv, N);
    k_scan1<<<nScanBlk, SCAN_B, 0, stream>>>(counts, rowptr, bsum, N);
    k_scan2<<<1, 512, 0, stream>>>(bsum, nScanBlk);
    k_scan3<<<nScanBlk, SCAN_B, 0, stream>>>(rowptr, bsum, N, E);
    k_scatter<<<gE, blk, 0, stream>>>(ei, rank, rowptr, sorted, E);
    k_bounds<<<gN, blk, 0, stream>>>(batch, gstart, N);
    k_wsplit<64><<<(64 * HID + 255) / 256, blk, 0, stream>>>(W1, wf1h, wf1l);
    k_wsplit<128><<<(128 * HID + 255) / 256, blk, 0, stream>>>(W2, wf2h, wf2l);
    k_wsplit<128><<<(128 * HID + 255) / 256, blk, 0, stream>>>(W3, wf3h, wf3l);

    // ---- 3 GCN layers: MFMA GEMM (dinv folded) -> plain-sum aggregate ----
    k_gemm_mfma<64, false><<<mfmaGrid, blk, 0, stream>>>(x, wf1h, wf1l, dinv, hW, N);
    k_aggr<<<aggrGrid, blk, 0, stream>>>(rowptr, sorted, hW, dinv, b1, bufB, N);
    k_gemm_mfma<128, true><<<mfmaGrid, blk, 0, stream>>>(bufB, wf2h, wf2l, dinv, hW, N);
    k_aggr<<<aggrGrid, blk, 0, stream>>>(rowptr, sorted, hW, dinv, b2, bufB, N);
    k_gemm_mfma<128, true><<<mfmaGrid, blk, 0, stream>>>(bufB, wf3h, wf3l, dinv, hW, N);
    k_aggr<<<aggrGrid, blk, 0, stream>>>(rowptr, sorted, hW, dinv, b3, bufB, N);

    // ---- fused mean pool + classifier ----
    k_poolfinal<<<NG, blk, 0, stream>>>(bufB, gstart, Wl, bl, out);
}

// Round 9
// 457.480 us; speedup vs baseline: 1.1036x; 1.1036x over previous
//
#include <hip/hip_runtime.h>
#include <math.h>

#define HID 128
#define NOUT 10
#define NG 1000
#define SCAN_B 256

typedef unsigned short u16;
typedef __attribute__((ext_vector_type(8))) short bf16x8;
typedef __attribute__((ext_vector_type(8))) unsigned short u16x8;
typedef __attribute__((ext_vector_type(4))) float f32x4;

__device__ inline u16 f2bf(float f) {
    unsigned x = __float_as_uint(f);
    return (u16)((x + 0x7FFF + ((x >> 16) & 1)) >> 16);  // RNE
}
__device__ inline float bf2f(u16 b) { return __uint_as_float(((unsigned)b) << 16); }

__global__ void k_zero(float* __restrict__ p, int n) {
    int i = blockIdx.x * 256 + threadIdx.x;
    if (i < n) p[i] = 0.f;
}

// counts[d]++ AND capture per-edge rank (position within its dst bucket)
__global__ void k_count_rank(const int* __restrict__ ei, int* __restrict__ counts,
                             int* __restrict__ rank, int E) {
    int e = blockIdx.x * 256 + threadIdx.x;
    if (e < E) rank[e] = atomicAdd(&counts[ei[(size_t)E + e]], 1);
}

// block-local exclusive scan of counts -> rowptr; block sums -> bsum; also dinv
__global__ __launch_bounds__(SCAN_B) void k_scan1(const int* __restrict__ counts,
                                                  int* __restrict__ rowptr,
                                                  int* __restrict__ bsum,
                                                  float* __restrict__ dinv, int N) {
    __shared__ int s[SCAN_B];
    int t = threadIdx.x;
    int i = blockIdx.x * SCAN_B + t;
    int v = (i < N) ? counts[i] : 0;
    if (i < N) dinv[i] = rsqrtf((float)(v + 1));  // +1 self-loop
    s[t] = v;
    __syncthreads();
    for (int off = 1; off < SCAN_B; off <<= 1) {
        int u = (t >= off) ? s[t - off] : 0;
        __syncthreads();
        s[t] += u;
        __syncthreads();
    }
    if (i < N) rowptr[i] = s[t] - v;
    if (t == SCAN_B - 1) bsum[blockIdx.x] = s[t];
}

__global__ __launch_bounds__(512) void k_scan2(int* __restrict__ bsum, int nb) {
    __shared__ int s[512];
    int t = threadIdx.x;
    int v = (t < nb) ? bsum[t] : 0;
    s[t] = v;
    __syncthreads();
    for (int off = 1; off < 512; off <<= 1) {
        int u = (t >= off) ? s[t - off] : 0;
        __syncthreads();
        s[t] += u;
        __syncthreads();
    }
    if (t < nb) bsum[t] = s[t] - v;
}

__global__ void k_scan3(int* __restrict__ rowptr, const int* __restrict__ bsum, int N, int E) {
    int i = blockIdx.x * SCAN_B + threadIdx.x;
    if (i < N) rowptr[i] += bsum[blockIdx.x];
    if (i == 0) rowptr[N] = E;
}

// sorted[rowptr[d] + rank[e]] = src byte-offset (src*256) — saves addr math in aggr
__global__ void k_scatter(const int* __restrict__ ei, const int* __restrict__ rank,
                          const int* __restrict__ rowptr, int* __restrict__ sorted, int E) {
    int e = blockIdx.x * 256 + threadIdx.x;
    if (e >= E) return;
    int s = ei[e];
    int d = ei[(size_t)E + e];
    sorted[rowptr[d] + rank[e]] = s << 8;   // byte offset into g (HID*2 = 256 B rows)
}

__global__ void k_bounds(const int* __restrict__ batch, int* __restrict__ gstart, int N) {
    int i = blockIdx.x * 256 + threadIdx.x;
    if (i >= N) return;
    int cur = batch[i];
    if (i == 0) {
        for (int g = 0; g <= cur; ++g) gstart[g] = 0;
    } else {
        int prev = batch[i - 1];
        for (int g = prev + 1; g <= cur; ++g) gstart[g] = i;
    }
    if (i == N - 1) {
        for (int g = cur + 1; g <= NG; ++g) gstart[g] = N;
    }
}

// Pre-pack W[K][128] into lane-major MFMA B-fragments, hi/lo bf16 split.
template<int K>
__global__ void k_wsplit(const float* __restrict__ W, u16* __restrict__ whi, u16* __restrict__ wlo) {
    int idx = blockIdx.x * 256 + threadIdx.x;
    if (idx >= K * HID) return;
    int k = idx >> 7;
    int col = idx & 127;
    float v = W[idx];
    u16 hb = f2bf(v);
    u16 lb = f2bf(v - bf2f(hb));
    int ks = k >> 5;
    int kq = (k >> 3) & 3;
    int j = k & 7;
    int c = col >> 4;
    int r = col & 15;
    int lane = kq * 16 + r;
    size_t pos = ((size_t)(ks * 8 + c) * 64 + lane) * 8 + j;
    whi[pos] = hb;
    wlo[pos] = lb;
}

// g(bf16)[N][128] = dinv[row] * ((relu?)(in[N][K]) @ W) via MFMA hi/lo split.
// Round-7 shape: 16 rows per wave, no LDS, no launch-bounds cap.
template<int K, bool RELU_IN>
__global__ __launch_bounds__(256) void k_gemm_mfma(const float* __restrict__ in,
                                                   const u16* __restrict__ whi,
                                                   const u16* __restrict__ wlo,
                                                   const float* __restrict__ dinv,
                                                   u16* __restrict__ g, int N) {
    constexpr int NKS = K / 32;
    const int w = threadIdx.x >> 6;
    const int l = threadIdx.x & 63;
    const int row0 = blockIdx.x * 64 + w * 16;
    const int r = l & 15;
    const int q = l >> 4;

    int arow = row0 + r;
    if (arow > N - 1) arow = N - 1;
    const float* ap = in + (size_t)arow * K + q * 8;

    bf16x8 ahi[NKS], alo[NKS];
#pragma unroll
    for (int ks = 0; ks < NKS; ++ks) {
        float4 v0 = *(const float4*)(ap + ks * 32);
        float4 v1 = *(const float4*)(ap + ks * 32 + 4);
        float va[8] = {v0.x, v0.y, v0.z, v0.w, v1.x, v1.y, v1.z, v1.w};
#pragma unroll
        for (int j = 0; j < 8; ++j) {
            float f = va[j];
            if (RELU_IN) f = fmaxf(f, 0.f);
            u16 hb = f2bf(f);
            ahi[ks][j] = (short)hb;
            alo[ks][j] = (short)f2bf(f - bf2f(hb));
        }
    }

    f32x4 acc[8];
#pragma unroll
    for (int c = 0; c < 8; ++c) acc[c] = (f32x4){0.f, 0.f, 0.f, 0.f};

    const bf16x8* whiv = (const bf16x8*)whi;
    const bf16x8* wlov = (const bf16x8*)wlo;

#pragma unroll
    for (int ks = 0; ks < NKS; ++ks) {
#pragma unroll
        for (int c = 0; c < 8; ++c) {
            bf16x8 b = whiv[(size_t)(ks * 8 + c) * 64 + l];
            acc[c] = __builtin_amdgcn_mfma_f32_16x16x32_bf16(ahi[ks], b, acc[c], 0, 0, 0);
            acc[c] = __builtin_amdgcn_mfma_f32_16x16x32_bf16(alo[ks], b, acc[c], 0, 0, 0);
        }
    }
#pragma unroll
    for (int ks = 0; ks < NKS; ++ks) {
#pragma unroll
        for (int c = 0; c < 8; ++c) {
            bf16x8 b = wlov[(size_t)(ks * 8 + c) * 64 + l];
            acc[c] = __builtin_amdgcn_mfma_f32_16x16x32_bf16(ahi[ks], b, acc[c], 0, 0, 0);
        }
    }

    // epilogue: scale row by dinv, store bf16. D row=(l>>4)*4+i, col=c*16+(l&15)
    float dv[4];
#pragma unroll
    for (int i = 0; i < 4; ++i) {
        int rr = row0 + q * 4 + i;
        dv[i] = (rr < N) ? dinv[rr] : 0.f;
    }
#pragma unroll
    for (int c = 0; c < 8; ++c) {
#pragma unroll
        for (int i = 0; i < 4; ++i) {
            int rr = row0 + q * 4 + i;
            if (rr < N) g[(size_t)rr * HID + c * 16 + r] = f2bf(acc[c][i] * dv[i]);
        }
    }
}

// out[v] = b + dinv[v] * (g[v] + sum_{s in in-edges(v)} g[s])
// Round-7 shape: one wave64 per node, 4 quarter-wave streams, 2-deep unroll.
// sorted[] holds byte offsets (src*256) — no multiply on the gather path.
#define BFACC(a, p)                                   \
    a[0] += __uint_as_float((p).x << 16);             \
    a[1] += __uint_as_float((p).x & 0xffff0000u);     \
    a[2] += __uint_as_float((p).y << 16);             \
    a[3] += __uint_as_float((p).y & 0xffff0000u);     \
    a[4] += __uint_as_float((p).z << 16);             \
    a[5] += __uint_as_float((p).z & 0xffff0000u);     \
    a[6] += __uint_as_float((p).w << 16);             \
    a[7] += __uint_as_float((p).w & 0xffff0000u);

__global__ __launch_bounds__(256) void k_aggr(const int* __restrict__ rowptr,
                                              const int* __restrict__ sorted,
                                              const u16* __restrict__ g,
                                              const float* __restrict__ dinv,
                                              const float* __restrict__ b,
                                              float* __restrict__ out, int N) {
    int wid = threadIdx.x >> 6;
    int lane = threadIdx.x & 63;
    int v = blockIdx.x * 4 + wid;
    if (v >= N) return;
    int qq = lane >> 4;              // edge stream 0..3
    int r = lane & 15;
    int cb = r * 16;                 // byte offset of this lane's 8 columns

    const char* gb = (const char*)g;

    float a0[8], a1[8];
#pragma unroll
    for (int i = 0; i < 8; ++i) { a0[i] = 0.f; a1[i] = 0.f; }

    int beg = rowptr[v], end = rowptr[v + 1];
    int j = beg + qq;
    for (; j + 4 < end; j += 8) {
        int o0 = sorted[j];
        int o1 = sorted[j + 4];
        uint4 p0 = *(const uint4*)(gb + o0 + cb);
        uint4 p1 = *(const uint4*)(gb + o1 + cb);
        BFACC(a0, p0);
        BFACC(a1, p1);
    }
    for (; j < end; j += 4) {
        int o0 = sorted[j];
        uint4 p0 = *(const uint4*)(gb + o0 + cb);
        BFACC(a0, p0);
    }

#pragma unroll
    for (int i = 0; i < 8; ++i) {
        float t = a0[i] + a1[i];
        t += __shfl_xor(t, 16);
        t += __shfl_xor(t, 32);
        a0[i] = t;
    }

    if (qq == 0) {
        uint4 sv = *(const uint4*)(gb + ((size_t)v << 8) + cb);
        float se[8];
        se[0] = __uint_as_float(sv.x << 16); se[1] = __uint_as_float(sv.x & 0xffff0000u);
        se[2] = __uint_as_float(sv.y << 16); se[3] = __uint_as_float(sv.y & 0xffff0000u);
        se[4] = __uint_as_float(sv.z << 16); se[5] = __uint_as_float(sv.z & 0xffff0000u);
        se[6] = __uint_as_float(sv.w << 16); se[7] = __uint_as_float(sv.w & 0xffff0000u);
        float dv = dinv[v];
        int c8 = r * 8;
        float4 bv0 = *(const float4*)&b[c8];
        float4 bv1 = *(const float4*)&b[c8 + 4];
        float4 o0, o1;
        o0.x = bv0.x + dv * (a0[0] + se[0]);
        o0.y = bv0.y + dv * (a0[1] + se[1]);
        o0.z = bv0.z + dv * (a0[2] + se[2]);
        o0.w = bv0.w + dv * (a0[3] + se[3]);
        o1.x = bv1.x + dv * (a0[4] + se[4]);
        o1.y = bv1.y + dv * (a0[5] + se[5]);
        o1.z = bv1.z + dv * (a0[6] + se[6]);
        o1.w = bv1.w + dv * (a0[7] + se[7]);
        *(float4*)&out[(size_t)v * HID + c8] = o0;
        *(float4*)&out[(size_t)v * HID + c8 + 4] = o1;
    }
}

// fused mean-pool (relu on load) + classifier
__global__ __launch_bounds__(256) void k_poolfinal(const float* __restrict__ h,
                                                   const int* __restrict__ gstart,
                                                   const float* __restrict__ Wl,
                                                   const float* __restrict__ bl,
                                                   float* __restrict__ out) {
    __shared__ float pool[HID];
    int g = blockIdx.x;
    int t = threadIdx.x;
    int col = t & 127;
    int grp = t >> 7;
    int beg = gstart[g], end = gstart[g + 1];

    float acc = 0.f;
    for (int i = beg + grp; i < end; i += 2)
        acc += fmaxf(h[(size_t)i * HID + col], 0.f);

    if (grp == 1) pool[col] = acc;
    __syncthreads();
    if (grp == 0) {
        float tot = acc + pool[col];
        float c = fmaxf((float)(end - beg), 1.0f);
        pool[col] = tot / c;
    }
    __syncthreads();
    if (t < NOUT) {
        float a = bl[t];
        for (int k = 0; k < HID; ++k) a += pool[k] * Wl[k * NOUT + t];
        out[g * NOUT + t] = a;
    }
}

__global__ void k_probe(float* __restrict__ out, int n, float val) {
    int i = blockIdx.x * 256 + threadIdx.x;
    if (i < n) out[i] = val;
}

extern "C" void kernel_launch(void* const* d_in, const int* in_sizes, int n_in,
                              void* d_out, int out_size, void* d_ws, size_t ws_size,
                              hipStream_t stream) {
    const float* x    = (const float*)d_in[0];
    const int* ei     = (const int*)d_in[1];     // int64 ref -> int32 device
    const int* batch  = (const int*)d_in[2];
    const float* W1 = (const float*)d_in[3];
    const float* b1 = (const float*)d_in[4];
    const float* W2 = (const float*)d_in[5];
    const float* b2 = (const float*)d_in[6];
    const float* W3 = (const float*)d_in[7];
    const float* b3 = (const float*)d_in[8];
    const float* Wl = (const float*)d_in[9];
    const float* bl = (const float*)d_in[10];
    float* out = (float*)d_out;

    const int N = in_sizes[0] / 64;   // 100000
    const int E = in_sizes[1] / 2;    // 1600000

    // workspace layout (bytes)
    char* ws = (char*)d_ws;
    const size_t off_dinv   = 0;                        // N*4
    const size_t off_counts = 400000;                   // N*4
    const size_t off_rowptr = 800000;                   // (N+1)*4
    const size_t off_rank   = 1200128;                  // E*4
    const size_t off_bsum   = 7600128;                  // 512*4
    const size_t off_gstart = 7602176;                  // (NG+1)*4
    const size_t off_sorted = 7606400;                  // E*4
    const size_t off_hW     = 14006400;                 // N*HID*2
    const size_t off_bufB   = 39606400;                 // N*HID*4
    const size_t off_wf1h   = 90806400;                 // 64*128*2
    const size_t off_wf1l   = 90822784;
    const size_t off_wf2h   = 90839168;                 // 128*128*2
    const size_t off_wf2l   = 90871936;
    const size_t off_wf3h   = 90904704;
    const size_t off_wf3l   = 90937472;
    const size_t need       = 90970240;                 // ~91.0 MB

    if (ws_size < need) {
        float enc = (float)(ws_size >> 20);
        k_probe<<<(out_size + 255) / 256, 256, 0, stream>>>(out, out_size, enc);
        return;
    }

    float* dinv  = (float*)(ws + off_dinv);
    int* counts  = (int*)(ws + off_counts);
    int* rowptr  = (int*)(ws + off_rowptr);
    int* rank    = (int*)(ws + off_rank);
    int* bsum    = (int*)(ws + off_bsum);
    int* gstart  = (int*)(ws + off_gstart);
    int* sorted  = (int*)(ws + off_sorted);
    u16* hW      = (u16*)(ws + off_hW);
    float* bufB  = (float*)(ws + off_bufB);
    u16* wf1h = (u16*)(ws + off_wf1h);  u16* wf1l = (u16*)(ws + off_wf1l);
    u16* wf2h = (u16*)(ws + off_wf2h);  u16* wf2l = (u16*)(ws + off_wf2l);
    u16* wf3h = (u16*)(ws + off_wf3h);  u16* wf3l = (u16*)(ws + off_wf3l);

    dim3 blk(256);
    const int gN = (N + 255) / 256;
    const int gE = (E + 255) / 256;
    const int nScanBlk = (N + SCAN_B - 1) / SCAN_B;
    const int mfmaGrid = (N + 63) / 64;               // 16 rows/wave (round-7 shape)
    const int aggrGrid = (N + 3) / 4;

    // ---- CSR build + weight fragment packing ----
    k_zero<<<gN, blk, 0, stream>>>((float*)counts, N);
    k_count_rank<<<gE, blk, 0, stream>>>(ei, counts, rank, E);
    k_scan1<<<nScanBlk, SCAN_B, 0, stream>>>(counts, rowptr, bsum, dinv, N);
    k_scan2<<<1, 512, 0, stream>>>(bsum, nScanBlk);
    k_scan3<<<nScanBlk, SCAN_B, 0, stream>>>(rowptr, bsum, N, E);
    k_scatter<<<gE, blk, 0, stream>>>(ei, rank, rowptr, sorted, E);
    k_bounds<<<gN, blk, 0, stream>>>(batch, gstart, N);
    k_wsplit<64><<<(64 * HID + 255) / 256, blk, 0, stream>>>(W1, wf1h, wf1l);
    k_wsplit<128><<<(128 * HID + 255) / 256, blk, 0, stream>>>(W2, wf2h, wf2l);
    k_wsplit<128><<<(128 * HID + 255) / 256, blk, 0, stream>>>(W3, wf3h, wf3l);

    // ---- 3 GCN layers: MFMA GEMM (dinv folded) -> plain-sum aggregate ----
    k_gemm_mfma<64, false><<<mfmaGrid, blk, 0, stream>>>(x, wf1h, wf1l, dinv, hW, N);
    k_aggr<<<aggrGrid, blk, 0, stream>>>(rowptr, sorted, hW, dinv, b1, bufB, N);
    k_gemm_mfma<128, true><<<mfmaGrid, blk, 0, stream>>>(bufB, wf2h, wf2l, dinv, hW, N);
    k_aggr<<<aggrGrid, blk, 0, stream>>>(rowptr, sorted, hW, dinv, b2, bufB, N);
    k_gemm_mfma<128, true><<<mfmaGrid, blk, 0, stream>>>(bufB, wf3h, wf3l, dinv, hW, N);
    k_aggr<<<aggrGrid, blk, 0, stream>>>(rowptr, sorted, hW, dinv, b3, bufB, N);

    // ---- fused mean pool + classifier ----
    k_poolfinal<<<NG, blk, 0, stream>>>(bufB, gstart, Wl, bl, out);
}